// Round 5
// baseline (1141.651 us; speedup 1.0000x reference)
//
#include <hip/hip_runtime.h>
#include <math.h>

#define ISZ 256
#define KSEL 31      // keep top-(K+1) = 31
#define KCAND 34     // fp32 candidate superset size
#define NCAND 64
#define BM 64
#define BK 32

__device__ __forceinline__ unsigned fkey(float f) {
    unsigned u = __float_as_uint(f);
    return (u & 0x80000000u) ? ~u : (u | 0x80000000u);
}
__device__ __forceinline__ double h64_of(float f, float w0, float w1) {
    return fmax((double)f * (double)w0, 0.0) * (double)w1;
}

// E = fp32 normalized embedding (values); snorm = fp64 ||h|| (selection).
__global__ __launch_bounds__(256) void emb_kernel(const float* __restrict__ F,
                                                  const float* __restrict__ w0,
                                                  const float* __restrict__ w1,
                                                  float* __restrict__ E,
                                                  double* __restrict__ snorm,
                                                  int n) {
    int row = blockIdx.x;
    int t = threadIdx.x;
    float f = F[(size_t)row * ISZ + t];
    double h64 = h64_of(f, w0[t], w1[t]);
    double ss = h64 * h64;
#pragma unroll
    for (int off = 32; off; off >>= 1) ss += __shfl_down(ss, off);
    __shared__ double red[4];
    if ((t & 63) == 0) red[t >> 6] = ss;
    __syncthreads();
    double tot = red[0] + red[1] + red[2] + red[3];
    double s = fmax(sqrt(tot), 1e-12);
    if (t == 0) snorm[row] = s;
    E[(size_t)row * ISZ + t] = (float)(h64 / s);
}

// C = E*E^T fp32 (values only; 2e-2 tolerance). Symmetric tiles mirrored.
__global__ __launch_bounds__(256) void gemm_sym(const float* __restrict__ E,
                                                float* __restrict__ C, int n) {
    int bx = blockIdx.x, by = blockIdx.y;
    if (bx < by) return;
    const int row0 = by * BM, col0 = bx * BM;
    __shared__ alignas(16) float As[BK][BM + 4];
    __shared__ alignas(16) float Bs[BK][BM + 4];
    int tid = threadIdx.x;
    int tx = tid & 15, ty = tid >> 4;
    float acc[4][4] = {};
    for (int kt = 0; kt < ISZ; kt += BK) {
#pragma unroll
        for (int l = 0; l < 2; ++l) {
            int idx = tid + l * 256;
            int r = idx >> 3;
            int kq = idx & 7;
            int arow = min(row0 + r, n - 1);
            int brow = min(col0 + r, n - 1);
            float4 va = *(const float4*)&E[(size_t)arow * ISZ + kt + kq * 4];
            float4 vb = *(const float4*)&E[(size_t)brow * ISZ + kt + kq * 4];
            As[kq * 4 + 0][r] = va.x; As[kq * 4 + 1][r] = va.y;
            As[kq * 4 + 2][r] = va.z; As[kq * 4 + 3][r] = va.w;
            Bs[kq * 4 + 0][r] = vb.x; Bs[kq * 4 + 1][r] = vb.y;
            Bs[kq * 4 + 2][r] = vb.z; Bs[kq * 4 + 3][r] = vb.w;
        }
        __syncthreads();
#pragma unroll 8
        for (int kk = 0; kk < BK; ++kk) {
            float4 a4 = *(const float4*)&As[kk][ty * 4];
            float4 b4 = *(const float4*)&Bs[kk][tx * 4];
            float a[4] = {a4.x, a4.y, a4.z, a4.w};
            float b[4] = {b4.x, b4.y, b4.z, b4.w};
#pragma unroll
            for (int i = 0; i < 4; ++i)
#pragma unroll
                for (int j = 0; j < 4; ++j)
                    acc[i][j] = __builtin_fmaf(a[i], b[j], acc[i][j]);
        }
        __syncthreads();
    }
#pragma unroll
    for (int i = 0; i < 4; ++i) {
        int r = row0 + ty * 4 + i;
        if (r < n) {
            int c = col0 + tx * 4;
            if (c + 3 < n) {
                *(float4*)&C[(size_t)r * n + c] =
                    make_float4(acc[i][0], acc[i][1], acc[i][2], acc[i][3]);
            } else {
#pragma unroll
                for (int j = 0; j < 4; ++j)
                    if (c + j < n) C[(size_t)r * n + c + j] = acc[i][j];
            }
        }
    }
    if (bx > by) {
#pragma unroll
        for (int j = 0; j < 4; ++j) {
            int r2 = col0 + tx * 4 + j;
            if (r2 < n) {
#pragma unroll
                for (int i = 0; i < 4; ++i) {
                    int c2 = row0 + ty * 4 + i;
                    if (c2 < n) C[(size_t)r2 * n + c2] = acc[i][j];
                }
            }
        }
    }
}

// Per row: fp32 binary-search -> top-KCAND candidate superset; fp64 recompute
// of candidate sims from raw inputs (matches an fp64 numpy reference to
// ~1e-15); exact top-KSEL with stable lowest-index tie-break; masked relu.
__global__ __launch_bounds__(256) void topk_mask(float* __restrict__ C,
                                                 const float* __restrict__ F,
                                                 const float* __restrict__ W0,
                                                 const float* __restrict__ W1,
                                                 const double* __restrict__ snorm,
                                                 int n) {
    __shared__ unsigned keys[10000];
    __shared__ unsigned flags[313];   // 10000-bit keep mask
    __shared__ unsigned cnt[2];
    __shared__ int cand_idx[NCAND];
    __shared__ double cand_val[NCAND];
    __shared__ int ncand;
    int row = blockIdx.x;
    int tid = threadIdx.x;
    float* rowp = C + (size_t)row * n;
    int n4 = n >> 2;
    for (int q = tid; q < n4; q += 256) {
        float4 v = ((const float4*)rowp)[q];
        keys[q * 4 + 0] = fkey(v.x);
        keys[q * 4 + 1] = fkey(v.y);
        keys[q * 4 + 2] = fkey(v.z);
        keys[q * 4 + 3] = fkey(v.w);
    }
    for (int q = tid; q < 313; q += 256) flags[q] = 0;   // FULLY zeroed (round-2 bug fix)
    if (tid == 0) { cnt[0] = 0; cnt[1] = 0; ncand = 0; }
    __syncthreads();
    // ---- binary search: largest T with count(keys >= T) >= KCAND ----
    unsigned lo = 0u, hi = 0xFFFFFFFFu;
    int p = 0;
    while (lo < hi) {
        unsigned d = hi - lo;
        unsigned mid = lo + (d >> 1) + (d & 1u);
        int local = 0;
        for (int q = tid; q < n; q += 256) local += (keys[q] >= mid) ? 1 : 0;
#pragma unroll
        for (int off = 32; off; off >>= 1) local += __shfl_down(local, off);
        if ((tid & 63) == 0) atomicAdd(&cnt[p], (unsigned)local);
        __syncthreads();
        unsigned c = cnt[p];
        if (tid == 0) cnt[p ^ 1] = 0;
        __syncthreads();
        if (c >= KCAND) lo = mid; else hi = mid - 1;
        p ^= 1;
    }
    unsigned T = lo;
    // ---- collect candidate indices (>= KCAND of them) ----
    for (int q = tid; q < n; q += 256) {
        if (keys[q] >= T) {
            int s = atomicAdd(&ncand, 1);
            if (s < NCAND) cand_idx[s] = q;
        }
    }
    __syncthreads();
    int m = min(ncand, NCAND);
    // ---- fp64 recompute of candidate sims ----
    int lane = tid & 63, wid = tid >> 6;
    double hr[4];
    float w0e[4], w1e[4];
#pragma unroll
    for (int r = 0; r < 4; ++r) {
        int e = lane + 64 * r;
        w0e[r] = W0[e];
        w1e[r] = W1[e];
        hr[r] = h64_of(F[(size_t)row * ISZ + e], w0e[r], w1e[r]);
    }
    for (int c = wid; c < m; c += 4) {
        int j = cand_idx[c];
        double acc = 0.0;
#pragma unroll
        for (int r = 0; r < 4; ++r) {
            int e = lane + 64 * r;
            acc += hr[r] * h64_of(F[(size_t)j * ISZ + e], w0e[r], w1e[r]);
        }
#pragma unroll
        for (int off = 32; off; off >>= 1) acc += __shfl_down(acc, off);
        if (lane == 0) cand_val[c] = acc / snorm[j];   // row norm common factor dropped
    }
    __syncthreads();
    // ---- exact top-KSEL among candidates, stable lowest-index tie-break ----
    if (tid < m) {
        double v = cand_val[tid];
        int idx = cand_idx[tid];
        int rank = 0;
        for (int j2 = 0; j2 < m; ++j2) {
            double vj = cand_val[j2];
            rank += (vj > v || (vj == v && cand_idx[j2] < idx)) ? 1 : 0;
        }
        if (rank < KSEL) atomicOr(&flags[idx >> 5], 1u << (idx & 31));
    }
    __syncthreads();
    // ---- masked relu rewrite ----
    for (int q = tid; q < n; q += 256) {
        unsigned k = keys[q];
        bool keep = (flags[q >> 5] >> (q & 31)) & 1u;
        float v = (keep && k > 0x80000000u) ? __uint_as_float(k & 0x7FFFFFFFu)
                                            : 0.0f;
        rowp[q] = v;
    }
}

extern "C" void kernel_launch(void* const* d_in, const int* in_sizes, int n_in,
                              void* d_out, int out_size, void* d_ws, size_t ws_size,
                              hipStream_t stream) {
    const float* F  = (const float*)d_in[0];
    const float* w0 = (const float*)d_in[1];
    const float* w1 = (const float*)d_in[2];
    float* out = (float*)d_out;
    int isz = in_sizes[1];           // 256
    int n = in_sizes[0] / isz;       // 10000
    float* E = (float*)d_ws;
    double* snorm = (double*)((char*)d_ws + (size_t)n * ISZ * sizeof(float));

    emb_kernel<<<n, 256, 0, stream>>>(F, w0, w1, E, snorm, n);
    int nt = (n + BM - 1) / BM;
    gemm_sym<<<dim3(nt, nt), 256, 0, stream>>>(E, out, n);
    topk_mask<<<n, 256, 0, stream>>>(out, F, w0, w1, snorm, n);
}

// Round 6
// 890.558 us; speedup vs baseline: 1.2819x; 1.2819x over previous
//
#include <hip/hip_runtime.h>
#include <math.h>

#define ISZ 256
#define KSEL 31      // keep top-(K+1) = 31
#define CMIN 64      // min candidate count (margin for future bf16 GEMM)
#define NCAND 192    // max candidate count
#define BM 64
#define BK 32
#define NV 10        // float4 slots per thread: 10*4*256 = 10240 >= 10000

__device__ __forceinline__ double h64_of(float f, float w0, float w1) {
    return fmax((double)f * (double)w0, 0.0) * (double)w1;
}

// E = fp32 normalized embedding (values); snorm = fp64 ||h|| (selection).
__global__ __launch_bounds__(256) void emb_kernel(const float* __restrict__ F,
                                                  const float* __restrict__ w0,
                                                  const float* __restrict__ w1,
                                                  float* __restrict__ E,
                                                  double* __restrict__ snorm,
                                                  int n) {
    int row = blockIdx.x;
    int t = threadIdx.x;
    float f = F[(size_t)row * ISZ + t];
    double h64 = h64_of(f, w0[t], w1[t]);
    double ss = h64 * h64;
#pragma unroll
    for (int off = 32; off; off >>= 1) ss += __shfl_down(ss, off);
    __shared__ double red[4];
    if ((t & 63) == 0) red[t >> 6] = ss;
    __syncthreads();
    double tot = red[0] + red[1] + red[2] + red[3];
    double s = fmax(sqrt(tot), 1e-12);
    if (t == 0) snorm[row] = s;
    E[(size_t)row * ISZ + t] = (float)(h64 / s);
}

// C = E*E^T fp32 (values + candidate generation; exact selection is fp64).
__global__ __launch_bounds__(256) void gemm_sym(const float* __restrict__ E,
                                                float* __restrict__ C, int n) {
    int bx = blockIdx.x, by = blockIdx.y;
    if (bx < by) return;
    const int row0 = by * BM, col0 = bx * BM;
    __shared__ alignas(16) float As[BK][BM + 4];
    __shared__ alignas(16) float Bs[BK][BM + 4];
    int tid = threadIdx.x;
    int tx = tid & 15, ty = tid >> 4;
    float acc[4][4] = {};
    for (int kt = 0; kt < ISZ; kt += BK) {
#pragma unroll
        for (int l = 0; l < 2; ++l) {
            int idx = tid + l * 256;
            int r = idx >> 3;
            int kq = idx & 7;
            int arow = min(row0 + r, n - 1);
            int brow = min(col0 + r, n - 1);
            float4 va = *(const float4*)&E[(size_t)arow * ISZ + kt + kq * 4];
            float4 vb = *(const float4*)&E[(size_t)brow * ISZ + kt + kq * 4];
            As[kq * 4 + 0][r] = va.x; As[kq * 4 + 1][r] = va.y;
            As[kq * 4 + 2][r] = va.z; As[kq * 4 + 3][r] = va.w;
            Bs[kq * 4 + 0][r] = vb.x; Bs[kq * 4 + 1][r] = vb.y;
            Bs[kq * 4 + 2][r] = vb.z; Bs[kq * 4 + 3][r] = vb.w;
        }
        __syncthreads();
#pragma unroll 8
        for (int kk = 0; kk < BK; ++kk) {
            float4 a4 = *(const float4*)&As[kk][ty * 4];
            float4 b4 = *(const float4*)&Bs[kk][tx * 4];
            float a[4] = {a4.x, a4.y, a4.z, a4.w};
            float b[4] = {b4.x, b4.y, b4.z, b4.w};
#pragma unroll
            for (int i = 0; i < 4; ++i)
#pragma unroll
                for (int j = 0; j < 4; ++j)
                    acc[i][j] = __builtin_fmaf(a[i], b[j], acc[i][j]);
        }
        __syncthreads();
    }
#pragma unroll
    for (int i = 0; i < 4; ++i) {
        int r = row0 + ty * 4 + i;
        if (r < n) {
            int c = col0 + tx * 4;
            if (c + 3 < n) {
                *(float4*)&C[(size_t)r * n + c] =
                    make_float4(acc[i][0], acc[i][1], acc[i][2], acc[i][3]);
            } else {
#pragma unroll
                for (int j = 0; j < 4; ++j)
                    if (c + j < n) C[(size_t)r * n + c + j] = acc[i][j];
            }
        }
    }
    if (bx > by) {
#pragma unroll
        for (int j = 0; j < 4; ++j) {
            int r2 = col0 + tx * 4 + j;
            if (r2 < n) {
#pragma unroll
                for (int i = 0; i < 4; ++i) {
                    int c2 = row0 + ty * 4 + i;
                    if (c2 < n) C[(size_t)r2 * n + c2] = acc[i][j];
                }
            }
        }
    }
}

// Per row, register-resident: value-space bisection -> candidate superset
// (count in [CMIN, NCAND]); fp64 recompute from raw inputs for exact top-31
// (stable lowest-index ties); masked relu rewrite from registers; fp64 patch.
__global__ __launch_bounds__(256) void topk_mask(float* __restrict__ C,
                                                 const float* __restrict__ F,
                                                 const float* __restrict__ W0,
                                                 const float* __restrict__ W1,
                                                 const double* __restrict__ snorm,
                                                 int n) {
    __shared__ unsigned flags[320];   // 10000-bit keep mask (fully zeroed)
    __shared__ int redi[4];
    __shared__ int cand_idx[NCAND];
    __shared__ double cand_val[NCAND];
    __shared__ int ncand;
    int row = blockIdx.x;
    int tid = threadIdx.x;
    int lane = tid & 63, wid = tid >> 6;
    float* rowp = C + (size_t)row * n;

    // ---- load row into registers (coalesced float4) ----
    float4 v[NV];
#pragma unroll
    for (int s = 0; s < NV; ++s) {
        int e = 4 * tid + 1024 * s;
        if (e < n) v[s] = *(const float4*)&rowp[e];   // n%4==0
        else v[s] = make_float4(-1e30f, -1e30f, -1e30f, -1e30f);
    }
    for (int q = tid; q < 320; q += 256) flags[q] = 0;
    if (tid == 0) ncand = 0;
    __syncthreads();

    // ---- block count of (value >= t) ----
    auto blockcount = [&](float t) -> int {
        int c = 0;
#pragma unroll
        for (int s = 0; s < NV; ++s)
            c += (v[s].x >= t) + (v[s].y >= t) + (v[s].z >= t) + (v[s].w >= t);
#pragma unroll
        for (int off = 32; off; off >>= 1) c += __shfl_down(c, off);
        if (lane == 0) redi[wid] = c;
        __syncthreads();
        int tot = redi[0] + redi[1] + redi[2] + redi[3];
        __syncthreads();
        return tot;
    };

    // ---- bisection on value: find thr with count in [CMIN, NCAND] ----
    float lo = 0.0f, hi = 2.0f, thr = 0.0f;
    bool found = false;
    for (int it = 0; it < 24 && !found; ++it) {
        float mid = 0.5f * (lo + hi);
        int c = blockcount(mid);
        if (c > NCAND) lo = mid;
        else if (c < CMIN) hi = mid;
        else { thr = mid; found = true; }
    }
    if (!found) thr = lo;   // practically unreachable; collect caps at NCAND

    // ---- collect candidate indices ----
#pragma unroll
    for (int s = 0; s < NV; ++s) {
        int e = 4 * tid + 1024 * s;
        float vals[4] = {v[s].x, v[s].y, v[s].z, v[s].w};
#pragma unroll
        for (int j = 0; j < 4; ++j) {
            if (vals[j] >= thr) {
                int pos = atomicAdd(&ncand, 1);
                if (pos < NCAND) cand_idx[pos] = e + j;
            }
        }
    }
    __syncthreads();
    int m = min(ncand, NCAND);

    // ---- fp64 recompute of candidate sims from raw inputs ----
    double hr[4];
    float w0e[4], w1e[4];
#pragma unroll
    for (int r = 0; r < 4; ++r) {
        int e = lane + 64 * r;
        w0e[r] = W0[e];
        w1e[r] = W1[e];
        hr[r] = h64_of(F[(size_t)row * ISZ + e], w0e[r], w1e[r]);
    }
    double srow = snorm[row];
    for (int c = wid; c < m; c += 4) {
        int j = cand_idx[c];
        double acc = 0.0;
#pragma unroll
        for (int r = 0; r < 4; ++r) {
            int e = lane + 64 * r;
            acc += hr[r] * h64_of(F[(size_t)j * ISZ + e], w0e[r], w1e[r]);
        }
#pragma unroll
        for (int off = 32; off; off >>= 1) acc += __shfl_down(acc, off);
        if (lane == 0) cand_val[c] = acc / (srow * snorm[j]);  // true fp64 sim
    }
    __syncthreads();

    // ---- exact top-KSEL among candidates, stable lowest-index tie-break ----
    int myrank = KSEL;
    if (tid < m) {
        double vv = cand_val[tid];
        int idx = cand_idx[tid];
        int rank = 0;
        for (int j2 = 0; j2 < m; ++j2) {
            double vj = cand_val[j2];
            rank += (vj > vv || (vj == vv && cand_idx[j2] < idx)) ? 1 : 0;
        }
        myrank = rank;
        if (rank < KSEL) atomicOr(&flags[idx >> 5], 1u << (idx & 31));
    }
    __syncthreads();

    // ---- masked relu rewrite from registers ----
#pragma unroll
    for (int s = 0; s < NV; ++s) {
        int e = 4 * tid + 1024 * s;
        if (e >= n) continue;
        float vals[4] = {v[s].x, v[s].y, v[s].z, v[s].w};
        float o[4];
#pragma unroll
        for (int j = 0; j < 4; ++j) {
            int q = e + j;
            bool keep = (flags[q >> 5] >> (q & 31)) & 1u;
            o[j] = (keep && vals[j] > 0.0f) ? vals[j] : 0.0f;
        }
        *(float4*)&rowp[e] = make_float4(o[0], o[1], o[2], o[3]);
    }
    __syncthreads();   // order bulk writes before the patch

    // ---- fp64 value patch of kept entries ----
    if (tid < m && myrank < KSEL) {
        rowp[cand_idx[tid]] = (float)fmax(cand_val[tid], 0.0);
    }
}

extern "C" void kernel_launch(void* const* d_in, const int* in_sizes, int n_in,
                              void* d_out, int out_size, void* d_ws, size_t ws_size,
                              hipStream_t stream) {
    const float* F  = (const float*)d_in[0];
    const float* w0 = (const float*)d_in[1];
    const float* w1 = (const float*)d_in[2];
    float* out = (float*)d_out;
    int isz = in_sizes[1];           // 256
    int n = in_sizes[0] / isz;       // 10000
    float* E = (float*)d_ws;
    double* snorm = (double*)((char*)d_ws + (size_t)n * ISZ * sizeof(float));

    emb_kernel<<<n, 256, 0, stream>>>(F, w0, w1, E, snorm, n);
    int nt = (n + BM - 1) / BM;
    gemm_sym<<<dim3(nt, nt), 256, 0, stream>>>(E, out, n);
    topk_mask<<<n, 256, 0, stream>>>(out, F, w0, w1, snorm, n);
}

// Round 8
// 676.651 us; speedup vs baseline: 1.6872x; 1.3161x over previous
//
#include <hip/hip_runtime.h>
#include <hip/hip_bf16.h>
#include <math.h>

#define ISZ 256
#define KSEL 31      // keep top-(K+1) = 31
#define CMIN 64      // bisection window lower bound (margin over KSEL for bf16-GEMM error)
#define CEXIT 192    // bisection early-exit upper bound
#define NCAND 256    // candidate buffer cap (tie headroom)

typedef __attribute__((ext_vector_type(8))) short bf16x8;
typedef __attribute__((ext_vector_type(4))) float f32x4;

__device__ __forceinline__ double h64_of(float f, float w0, float w1) {
    return fmax((double)f * (double)w0, 0.0) * (double)w1;
}

// Eb = bf16 normalized embedding (MFMA operand); snorm = fp64 ||h||.
__global__ __launch_bounds__(256) void emb_kernel(const float* __restrict__ F,
                                                  const float* __restrict__ w0,
                                                  const float* __restrict__ w1,
                                                  __hip_bfloat16* __restrict__ Eb,
                                                  double* __restrict__ snorm,
                                                  int n) {
    int row = blockIdx.x;
    int t = threadIdx.x;
    float f = F[(size_t)row * ISZ + t];
    double h64 = h64_of(f, w0[t], w1[t]);
    double ss = h64 * h64;
#pragma unroll
    for (int off = 32; off; off >>= 1) ss += __shfl_down(ss, off);
    __shared__ double red[4];
    if ((t & 63) == 0) red[t >> 6] = ss;
    __syncthreads();
    double tot = red[0] + red[1] + red[2] + red[3];
    double s = fmax(sqrt(tot), 1e-12);
    if (t == 0) snorm[row] = s;
    Eb[(size_t)row * ISZ + t] = __float2bfloat16((float)(h64 / s));
}

// S = Eb * Eb^T via MFMA 16x16x32 bf16, fp32 output. 128x128 tile, 4 waves
// (2x2), each wave a 64x64 sub-tile. Fragments direct from global (operand is
// 5 MB, L2/L3-resident). Full grid — every store coalesced, no mirror scatter.
__global__ __launch_bounds__(256) void gemm_mfma(const __hip_bfloat16* __restrict__ Eb,
                                                 float* __restrict__ S, int n) {
    int bx = blockIdx.x, by = blockIdx.y;
    int row0 = by * 128, col0 = bx * 128;
    int tid = threadIdx.x, lane = tid & 63, wid = tid >> 6;
    int wr = wid >> 1, wc = wid & 1;
    int rbase = row0 + wr * 64 + (lane & 15);
    int cbase = col0 + wc * 64 + (lane & 15);
    int kg2 = ((lane >> 4) * 8) * 2;        // k-subgroup byte offset
    const char* Ep = (const char*)Eb;
    unsigned aoff[4], boff[4];
#pragma unroll
    for (int i = 0; i < 4; ++i) {
        aoff[i] = (unsigned)min(rbase + i * 16, n - 1) * (ISZ * 2) + kg2;
        boff[i] = (unsigned)min(cbase + i * 16, n - 1) * (ISZ * 2) + kg2;
    }
    f32x4 acc[4][4] = {};
#pragma unroll
    for (int kt = 0; kt < ISZ; kt += 32) {
        bf16x8 a[4], b[4];
#pragma unroll
        for (int i = 0; i < 4; ++i) a[i] = *(const bf16x8*)(Ep + aoff[i] + kt * 2);
#pragma unroll
        for (int j = 0; j < 4; ++j) b[j] = *(const bf16x8*)(Ep + boff[j] + kt * 2);
#pragma unroll
        for (int i = 0; i < 4; ++i)
#pragma unroll
            for (int j = 0; j < 4; ++j)
                acc[i][j] = __builtin_amdgcn_mfma_f32_16x16x32_bf16(a[i], b[j], acc[i][j], 0, 0, 0);
    }
    // C/D layout: col = lane&15, row = (lane>>4)*4 + r  [m89-verified]
    int orow = row0 + wr * 64 + (lane >> 4) * 4;
    int ocol = col0 + wc * 64 + (lane & 15);
#pragma unroll
    for (int i = 0; i < 4; ++i)
#pragma unroll
        for (int r = 0; r < 4; ++r) {
            int rr = orow + i * 16 + r;
            if (rr < n) {
#pragma unroll
                for (int j = 0; j < 4; ++j) {
                    int cc = ocol + j * 16;
                    if (cc < n) S[(size_t)rr * n + cc] = acc[i][j][r];
                }
            }
        }
}

// Per row (round-6-proven structure): register-resident fp32 row, value-space
// bisection to a candidate superset (count in [CMIN, CEXIT]), fp64 recompute
// from raw inputs (2-way ILP) for exact top-KSEL with stable lowest-index
// ties, flags bitmask, masked relu rewrite from registers, fp64 value patch.
__global__ __launch_bounds__(256) void topk_mask(float* __restrict__ C,
                                                 const float* __restrict__ F,
                                                 const float* __restrict__ W0,
                                                 const float* __restrict__ W1,
                                                 const double* __restrict__ snorm,
                                                 int n) {
    __shared__ unsigned flags[320];   // 10000-bit keep mask
    __shared__ int redi[4];
    __shared__ int cand_idx[NCAND];
    __shared__ double cand_val[NCAND];
    __shared__ int ncand;
    int row = blockIdx.x;
    int tid = threadIdx.x;
    int lane = tid & 63, wid = tid >> 6;
    float* rowp = C + (size_t)row * n;

    // ---- load row into registers (coalesced float4) ----
    float v[40];
#pragma unroll
    for (int s = 0; s < 10; ++s) {
        int e = 4 * tid + 1024 * s;
        if (e < n) {
            float4 w = *(const float4*)(rowp + e);
            v[s * 4 + 0] = w.x; v[s * 4 + 1] = w.y;
            v[s * 4 + 2] = w.z; v[s * 4 + 3] = w.w;
        } else {
#pragma unroll
            for (int q = 0; q < 4; ++q) v[s * 4 + q] = -1e30f;
        }
    }
    for (int q = tid; q < 320; q += 256) flags[q] = 0;
    if (tid == 0) ncand = 0;
    __syncthreads();

    auto blockcount = [&](float t) -> int {
        int c = 0;
#pragma unroll
        for (int q = 0; q < 40; ++q) c += (v[q] >= t) ? 1 : 0;
#pragma unroll
        for (int off = 32; off; off >>= 1) c += __shfl_down(c, off);
        if (lane == 0) redi[wid] = c;
        __syncthreads();
        int tot = redi[0] + redi[1] + redi[2] + redi[3];
        __syncthreads();
        return tot;
    };

    // Invariant: count(>=lo) > CEXIT (or window hit), count(>=hi) < CMIN.
    // count(>=0.75) == 1 (diag only) < CMIN, count(>=0) ~ n/2 > CEXIT.
    float lo = 0.0f, hi = 0.75f, thr = 0.0f;
    bool found = false;
    for (int it = 0; it < 30 && !found; ++it) {
        float mid = 0.5f * (lo + hi);
        int c = blockcount(mid);
        if (c >= CMIN && c <= CEXIT) { thr = mid; found = true; }
        else if (c >= CMIN) lo = mid;
        else hi = mid;
    }
    if (!found) thr = lo;   // fp32 values: window miss needs 129+ one-ulp ties

    // ---- collect candidate indices ----
#pragma unroll
    for (int s = 0; s < 10; ++s) {
        int e = 4 * tid + 1024 * s;
#pragma unroll
        for (int j = 0; j < 4; ++j) {
            if (v[s * 4 + j] >= thr) {
                int pos = atomicAdd(&ncand, 1);
                if (pos < NCAND) cand_idx[pos] = e + j;
            }
        }
    }
    __syncthreads();
    int m = min(ncand, NCAND);

    // ---- fp64 recompute from raw inputs, 2 candidates/iter for load ILP ----
    double hr[4];
    float w0e[4], w1e[4];
#pragma unroll
    for (int r = 0; r < 4; ++r) {
        int e = lane + 64 * r;
        w0e[r] = W0[e];
        w1e[r] = W1[e];
        hr[r] = h64_of(F[(size_t)row * ISZ + e], w0e[r], w1e[r]);
    }
    double srow = snorm[row];
    for (int c = wid * 2; c < m; c += 8) {
        int j1 = cand_idx[c];
        int c2ok = (c + 1 < m);
        int j2 = c2ok ? cand_idx[c + 1] : j1;
        double a1 = 0.0, a2 = 0.0;
#pragma unroll
        for (int r = 0; r < 4; ++r) {
            int e = lane + 64 * r;
            float f1 = F[(size_t)j1 * ISZ + e];
            float f2 = F[(size_t)j2 * ISZ + e];
            a1 += hr[r] * h64_of(f1, w0e[r], w1e[r]);
            a2 += hr[r] * h64_of(f2, w0e[r], w1e[r]);
        }
#pragma unroll
        for (int off = 32; off; off >>= 1) {
            a1 += __shfl_down(a1, off);
            a2 += __shfl_down(a2, off);
        }
        if (lane == 0) {
            cand_val[c] = a1 / (srow * snorm[j1]);
            if (c2ok) cand_val[c + 1] = a2 / (srow * snorm[j2]);
        }
    }
    __syncthreads();

    // ---- exact top-KSEL among candidates, stable lowest-index ties ----
    int myrank = KSEL;
    if (tid < m) {
        double vv = cand_val[tid];
        int idx = cand_idx[tid];
        int rank = 0;
        for (int j2 = 0; j2 < m; ++j2) {
            double vj = cand_val[j2];
            rank += (vj > vv || (vj == vv && cand_idx[j2] < idx)) ? 1 : 0;
        }
        myrank = rank;
        if (rank < KSEL) atomicOr(&flags[idx >> 5], 1u << (idx & 31));
    }
    __syncthreads();

    // ---- masked relu rewrite from registers ----
#pragma unroll
    for (int s = 0; s < 10; ++s) {
        int e = 4 * tid + 1024 * s;
        if (e >= n) continue;
        float vals[4] = {v[s * 4 + 0], v[s * 4 + 1], v[s * 4 + 2], v[s * 4 + 3]};
        float o[4];
#pragma unroll
        for (int j = 0; j < 4; ++j) {
            int q = e + j;
            bool keep = (flags[q >> 5] >> (q & 31)) & 1u;
            o[j] = (keep && vals[j] > 0.0f) ? vals[j] : 0.0f;
        }
        *(float4*)(rowp + e) = make_float4(o[0], o[1], o[2], o[3]);
    }
    __syncthreads();   // order bulk writes before the patch

    // ---- fp64 value patch of kept entries ----
    if (tid < m && myrank < KSEL) {
        rowp[cand_idx[tid]] = (float)fmax(cand_val[tid], 0.0);
    }
}

extern "C" void kernel_launch(void* const* d_in, const int* in_sizes, int n_in,
                              void* d_out, int out_size, void* d_ws, size_t ws_size,
                              hipStream_t stream) {
    const float* F  = (const float*)d_in[0];
    const float* w0 = (const float*)d_in[1];
    const float* w1 = (const float*)d_in[2];
    float* out = (float*)d_out;
    int isz = in_sizes[1];           // 256
    int n = in_sizes[0] / isz;       // 10000

    char* ws = (char*)d_ws;
    __hip_bfloat16* Ebf = (__hip_bfloat16*)ws;              // 5.12 MB
    double* snorm = (double*)(ws + (size_t)n * ISZ * 2);    // 80 KB

    emb_kernel<<<n, 256, 0, stream>>>(F, w0, w1, Ebf, snorm, n);
    int nt = (n + 127) / 128;
    gemm_mfma<<<dim3(nt, nt), 256, 0, stream>>>(Ebf, out, n);
    topk_mask<<<n, 256, 0, stream>>>(out, F, w0, w1, snorm, n);
}